// Round 5
// baseline (540.851 us; speedup 1.0000x reference)
//
#include <hip/hip_runtime.h>
#include <stdint.h>

#define NTOK 4096   // B*S = 2*2048
#define DDIM 1024
#define HDIM 2048
#define NEXP 8
#define TOPK 2

typedef short bf16x8 __attribute__((ext_vector_type(8)));
typedef float f32x4 __attribute__((ext_vector_type(4)));

__device__ __forceinline__ unsigned short f2bf(float f) {
    union { float f; unsigned int u; } v; v.f = f;
    unsigned int r = v.u + 0x7fffu + ((v.u >> 16) & 1u);
    return (unsigned short)(r >> 16);
}

__device__ __forceinline__ void gload16(const void* g, void* l) {
    __builtin_amdgcn_global_load_lds(
        (const __attribute__((address_space(1))) unsigned int*)g,
        (__attribute__((address_space(3))) unsigned int*)l, 16, 0, 0);
}

// ---------------- gating: logits, top-2, gates, counts; also x -> bf16 ----------------
__global__ __launch_bounds__(256) void k_gate(
    const float* __restrict__ x, const float* __restrict__ gw,
    unsigned short* __restrict__ xb, int* __restrict__ cnt,
    int* __restrict__ topi, float* __restrict__ topg)
{
    int w = threadIdx.x >> 6, ln = threadIdx.x & 63;
    int n = blockIdx.x * 4 + w;
    const float* xr = x + (size_t)n * DDIM;
    float p[NEXP];
#pragma unroll
    for (int e = 0; e < NEXP; e++) p[e] = 0.f;
#pragma unroll
    for (int j = 0; j < DDIM / 64; j++) {
        int idx = ln + 64 * j;
        float xv = xr[idx];
        xb[(size_t)n * DDIM + idx] = f2bf(xv);
#pragma unroll
        for (int e = 0; e < NEXP; e++) p[e] += xv * gw[e * DDIM + idx];
    }
#pragma unroll
    for (int off = 32; off >= 1; off >>= 1) {
#pragma unroll
        for (int e = 0; e < NEXP; e++) p[e] += __shfl_xor(p[e], off, 64);
    }
    if (ln == 0) {
        int i0 = 0; float v0 = p[0];
#pragma unroll
        for (int e = 1; e < NEXP; e++) if (p[e] > v0) { v0 = p[e]; i0 = e; }
        int i1 = -1; float v1 = -3.0e38f;
#pragma unroll
        for (int e = 0; e < NEXP; e++) if (e != i0 && p[e] > v1) { v1 = p[e]; i1 = e; }
        float g0 = 1.f / (1.f + __expf(v1 - v0));  // softmax of [v0,v1], v0 >= v1
        float g1 = 1.f - g0;
        atomicAdd(&cnt[i0], 1); atomicAdd(&cnt[i1], 1);
        topi[n * 2] = i0; topi[n * 2 + 1] = i1;
        topg[n * 2] = g0; topg[n * 2 + 1] = g1;
    }
}

// ---------------- prefix-sum over expert counts + aux loss ----------------
__global__ void k_scan(const int* __restrict__ cnt, int* __restrict__ offs,
                       float* __restrict__ auxout)
{
    if (threadIdx.x == 0) {
        int o = 0; float aux = 0.f;
#pragma unroll
        for (int e = 0; e < NEXP; e++) {
            offs[e] = o; o += cnt[e];
            float l = (float)cnt[e] / (float)(NTOK * TOPK);
            aux += l * l;
        }
        offs[NEXP] = o;
        auxout[0] = 0.01f * (float)NEXP * aux;
    }
}

// ---------------- scatter token ids / gate weights into expert buckets ----------------
__global__ __launch_bounds__(256) void k_scatter(
    const int* __restrict__ topi, const float* __restrict__ topg,
    const int* __restrict__ offs, int* __restrict__ fill,
    int* __restrict__ tok, float* __restrict__ gate)
{
    int g = blockIdx.x * 256 + threadIdx.x;
    if (g >= NTOK * TOPK) return;
    int e = topi[g];
    int pos = atomicAdd(&fill[e], 1);
    int slot = offs[e] + pos;
    tok[slot] = g >> 1;
    gate[slot] = topg[g];
}

// ---------------- fp32 -> bf16 weight conversion ----------------
__global__ __launch_bounds__(256) void k_conv(
    const float4* __restrict__ w1, const float4* __restrict__ w2,
    ushort4* __restrict__ w1b, ushort4* __restrict__ w2b)
{
    const int t1 = NEXP * HDIM * DDIM / 4;   // 4,194,304 vec4
    int stride = gridDim.x * blockDim.x;
    for (int i = blockIdx.x * 256 + threadIdx.x; i < 2 * t1; i += stride) {
        float4 v = (i < t1) ? w1[i] : w2[i - t1];
        ushort4 o;
        o.x = f2bf(v.x); o.y = f2bf(v.y); o.z = f2bf(v.z); o.w = f2bf(v.w);
        if (i < t1) w1b[i] = o; else w2b[i - t1] = o;
    }
}

// =====================================================================================
// m201-geometry 8-phase FFN GEMM: BM=BN=256, BK=64, 512 thr = 8 waves (2M x 4N),
// wave-tile 128x64 = 8x4 frags of mfma_f32_16x16x32_bf16, 16-MFMA phase clusters.
// LDS: per buffer A 2 halves x 16KB + B 2 halves x 16KB = 64KB; x2 dbuf = 128KB.
// A-half h = rows {wm*128 + h*64 + j}; B-half h = cols {wn*64 + h*32 + j} (row-permuted
// so each LDS half is ds_read in exactly ONE phase -> overwritable next phase).
// Swizzle: 16B chunk ^= (ldsrow & 7), applied on global SOURCE (LDS dest stays linear
// for global_load_lds) and on the ds_read chunk index.
// Register sets: aA (mh0, held P0&P3), aB (mh1, held P1&P2), bb (reloaded per n-half).
// Per-phase ds_reads: 12/8/4/0. Stage rotation (2 gload_lds per slot):
//   P0:A1(b1,t+1) P1:A0(b0,t+2) P2:B0(b0,t+2) P3:B1(b0,t+2)+vmcnt(6) P4:A1(b0,t+2)
//   P5:A0(b1,t+3) P6:B0(b1,t+3) P7:B1(b1,t+3)+vmcnt(6).  vmcnt N = 2 loads/half x 3
//   half-tiles in flight. Last iter: only P0's stage; vmcnt(0) at P3.
// FFN2 uses split-K=2 (blockIdx.z): KTOT=2048 -> 32 tiles -> TBLK=16 per z-block.
// (Round-4 bug: TBLK=8 dropped half of FFN2's K reduction.)
// =====================================================================================

#define VMCNT(n) asm volatile("s_waitcnt vmcnt(" #n ")" ::: "memory")
#define SBAR do { __builtin_amdgcn_sched_barrier(0); __builtin_amdgcn_s_barrier(); } while(0)
#define PRIO1 __builtin_amdgcn_s_setprio(1)
#define PRIO0 __builtin_amdgcn_s_setprio(0)

#define ST_A(b,h,tt) do { \
    gload16(aSrc[h][0] + (size_t)(tt)*64, smem + (b)*65536 + (h)*16384 +        w*1024); \
    gload16(aSrc[h][1] + (size_t)(tt)*64, smem + (b)*65536 + (h)*16384 + 8192 + w*1024); } while(0)
#define ST_B(b,h,tt) do { \
    gload16(bSrc[h][0] + (size_t)(tt)*64, smem + (b)*65536 + 32768 + (h)*16384 +        w*1024); \
    gload16(bSrc[h][1] + (size_t)(tt)*64, smem + (b)*65536 + 32768 + (h)*16384 + 8192 + w*1024); } while(0)

#define LDA(DST,b,mh) do { _Pragma("unroll") for (int mi=0;mi<4;mi++) { _Pragma("unroll") for (int ks=0;ks<2;ks++) { \
    DST[mi][ks] = *(const bf16x8*)(smem + (b)*65536 + (mh)*16384 + (wm*64 + mi*16 + ln15)*128 + colx[ks]); }} } while(0)
#define LDB(b,nh) do { _Pragma("unroll") for (int ni=0;ni<2;ni++) { _Pragma("unroll") for (int ks=0;ks<2;ks++) { \
    bb[ni][ks] = *(const bf16x8*)(smem + (b)*65536 + 32768 + (nh)*16384 + (wn*32 + ni*16 + ln15)*128 + colx[ks]); }} } while(0)
#define QUAD16(mh,nh,ASET) do { _Pragma("unroll") for (int mi=0;mi<4;mi++) { _Pragma("unroll") for (int ni=0;ni<2;ni++) { _Pragma("unroll") for (int ks=0;ks<2;ks++) { \
    acc[(mh)*4+mi][(nh)*2+ni] = __builtin_amdgcn_mfma_f32_16x16x32_bf16(ASET[mi][ks], bb[ni][ks], acc[(mh)*4+mi][(nh)*2+ni], 0,0,0); }}} } while(0)

#define ITER(LAST, t) do { \
  /* P0 (mh0,nh0) tile t buf0 */ \
  LDA(aA,0,0); LDB(0,0); ST_A(1,1,(t)+1); \
  SBAR; PRIO1; QUAD16(0,0,aA); PRIO0; SBAR; \
  /* P1 (mh1,nh0) */ \
  LDA(aB,0,1); if(!(LAST)) ST_A(0,0,(t)+2); \
  SBAR; PRIO1; QUAD16(1,0,aB); PRIO0; SBAR; \
  /* P2 (mh1,nh1) */ \
  LDB(0,1); if(!(LAST)) ST_B(0,0,(t)+2); \
  SBAR; PRIO1; QUAD16(1,1,aB); PRIO0; SBAR; \
  /* P3 (mh0,nh1), tile-boundary vmcnt */ \
  if(!(LAST)) ST_B(0,1,(t)+2); \
  SBAR; PRIO1; QUAD16(0,1,aA); PRIO0; \
  if(LAST) { VMCNT(0); } else { VMCNT(6); } SBAR; \
  /* P4 (mh0,nh0) tile t+1 buf1 */ \
  LDA(aA,1,0); LDB(1,0); if(!(LAST)) ST_A(0,1,(t)+2); \
  SBAR; PRIO1; QUAD16(0,0,aA); PRIO0; SBAR; \
  /* P5 (mh1,nh0) */ \
  LDA(aB,1,1); if(!(LAST)) ST_A(1,0,(t)+3); \
  SBAR; PRIO1; QUAD16(1,0,aB); PRIO0; SBAR; \
  /* P6 (mh1,nh1) */ \
  LDB(1,1); if(!(LAST)) ST_B(1,0,(t)+3); \
  SBAR; PRIO1; QUAD16(1,1,aB); PRIO0; SBAR; \
  /* P7 (mh0,nh1) */ \
  if(!(LAST)) ST_B(1,1,(t)+3); \
  SBAR; PRIO1; QUAD16(0,1,aA); PRIO0; \
  if(!(LAST)) { VMCNT(6); } SBAR; \
} while(0)

// KTOT = full K (row pitch of A and W); TBLK = K-tiles per block (split-K via blockIdx.z)
template<int KTOT, int TBLK, bool IS_FFN1>
__global__ __launch_bounds__(512, 2) void k_ffn8(
    const unsigned short* __restrict__ Abase,
    const unsigned short* __restrict__ Wb,
    const float* __restrict__ bias,
    const int* __restrict__ offs,
    const int* __restrict__ tok,
    const float* __restrict__ gate,
    unsigned short* __restrict__ hbuf,
    float* __restrict__ out)
{
    constexpr int NCOLS = IS_FFN1 ? HDIM : DDIM;

    int e = blockIdx.y & 7, rt = blockIdx.y >> 3;
    int soff = offs[e];
    int n_e = offs[e + 1] - soff;
    int row0 = rt * 256;
    if (row0 >= n_e) return;               // block-uniform exit, before any barrier
    int ncol0 = blockIdx.x * 256;
    int koff = blockIdx.z * (TBLK * 64);

    __shared__ __align__(16) char smem[131072];

    int tid = threadIdx.x;
    int w = tid >> 6, ln = tid & 63;
    int wm = w >> 2, wn = w & 3;
    int ln15 = ln & 15, g4 = ln >> 4;
    int colx[2];
#pragma unroll
    for (int ks = 0; ks < 2; ks++) colx[ks] = ((ks * 4 + g4) ^ (ln15 & 7)) * 16;

    // ---- per-lane stage source pointers (swizzle pre-applied on global address) ----
    const unsigned short* aSrc[2][2];
#pragma unroll
    for (int h = 0; h < 2; h++)
#pragma unroll
        for (int i = 0; i < 2; i++) {
            int rho = i * 64 + (tid >> 3);
            int trow = (rho >> 6) * 128 + h * 64 + (rho & 63);
            int csrc = (tid & 7) ^ (rho & 7);
            int r = row0 + trow; if (r > n_e - 1) r = n_e - 1;
            size_t grow = IS_FFN1 ? (size_t)tok[soff + r] : (size_t)(soff + r);
            aSrc[h][i] = Abase + grow * KTOT + koff + csrc * 8;
        }
    const unsigned short* Wexp = Wb + (size_t)e * NCOLS * KTOT;
    const unsigned short* bSrc[2][2];
#pragma unroll
    for (int h = 0; h < 2; h++)
#pragma unroll
        for (int i = 0; i < 2; i++) {
            int rho = i * 64 + (tid >> 3);
            int tcol = (rho >> 5) * 64 + h * 32 + (rho & 31);
            int csrc = (tid & 7) ^ (rho & 7);
            bSrc[h][i] = Wexp + (size_t)(ncol0 + tcol) * KTOT + koff + csrc * 8;
        }

    f32x4 acc[8][4];
#pragma unroll
    for (int m = 0; m < 8; m++)
#pragma unroll
        for (int n = 0; n < 4; n++) acc[m][n] = (f32x4)0.f;

    bf16x8 aA[4][2], aB[4][2], bb[2][2];

    // ---- prologue: tile0 (buf0) fully, tile1 (buf1) minus A1 = 14 loads; 6 stay in flight
    ST_A(0, 0, 0);
    ST_B(0, 0, 0);
    ST_A(0, 1, 0);
    ST_B(0, 1, 0);
    ST_A(1, 0, 1);
    ST_B(1, 0, 1);
    ST_B(1, 1, 1);
    VMCNT(6);
    SBAR;

    for (int t = 0; t + 2 < TBLK; t += 2) ITER(false, t);
    ITER(true, TBLK - 2);

    // ---- epilogue: C frag layout col=ln15 (n-side), row=g4*4+q (m-side) ----
    if (IS_FFN1) {
        float bv[4];
#pragma unroll
        for (int nj = 0; nj < 4; nj++)
            bv[nj] = bias[e * NCOLS + ncol0 + wn * 64 + nj * 16 + ln15];
#pragma unroll
        for (int mi = 0; mi < 8; mi++) {
#pragma unroll
            for (int q = 0; q < 4; q++) {
                int r = row0 + wm * 128 + mi * 16 + g4 * 4 + q;
                if (r < n_e) {
#pragma unroll
                    for (int nj = 0; nj < 4; nj++) {
                        int col = ncol0 + wn * 64 + nj * 16 + ln15;
                        float v = acc[mi][nj][q] + bv[nj];
                        float s = v / (1.f + __expf(-v));   // silu
                        hbuf[(size_t)(soff + r) * HDIM + col] = f2bf(s);
                    }
                }
            }
        }
    } else {
        float bv[4];
#pragma unroll
        for (int nj = 0; nj < 4; nj++)
            bv[nj] = (koff == 0) ? bias[e * NCOLS + ncol0 + wn * 64 + nj * 16 + ln15] : 0.f;
#pragma unroll
        for (int mi = 0; mi < 8; mi++) {
#pragma unroll
            for (int q = 0; q < 4; q++) {
                int r = row0 + wm * 128 + mi * 16 + g4 * 4 + q;
                if (r < n_e) {
                    int tk = tok[soff + r];
                    float gt = gate[soff + r];
#pragma unroll
                    for (int nj = 0; nj < 4; nj++) {
                        int col = ncol0 + wn * 64 + nj * 16 + ln15;
                        float v = gt * (acc[mi][nj][q] + bv[nj]);
                        atomicAdd(&out[(size_t)tk * DDIM + col], v);
                    }
                }
            }
        }
    }
}

extern "C" void kernel_launch(void* const* d_in, const int* in_sizes, int n_in,
                              void* d_out, int out_size, void* d_ws, size_t ws_size,
                              hipStream_t stream)
{
    const float* x  = (const float*)d_in[0];
    const float* gw = (const float*)d_in[1];
    const float* w1 = (const float*)d_in[2];
    const float* b1 = (const float*)d_in[3];
    const float* w2 = (const float*)d_in[4];
    const float* b2 = (const float*)d_in[5];
    float* out = (float*)d_out;

    char* ws = (char*)d_ws;
    size_t off = 0;
    auto alloc = [&](size_t bytes) {
        char* p = ws + off; off += (bytes + 255) & ~(size_t)255; return p;
    };
    unsigned short* xb  = (unsigned short*)alloc((size_t)NTOK * DDIM * 2);           // 8.4 MB
    unsigned short* w1b = (unsigned short*)alloc((size_t)NEXP * HDIM * DDIM * 2);    // 33.5 MB
    unsigned short* w2b = (unsigned short*)alloc((size_t)NEXP * DDIM * HDIM * 2);    // 33.5 MB
    unsigned short* hb  = (unsigned short*)alloc((size_t)NTOK * TOPK * HDIM * 2);    // 33.5 MB
    int*   tok  = (int*)alloc(NTOK * TOPK * 4);
    float* gate = (float*)alloc(NTOK * TOPK * 4);
    int*   topi = (int*)alloc(NTOK * TOPK * 4);
    float* topg = (float*)alloc(NTOK * TOPK * 4);
    int*   ctrl = (int*)alloc(256);   // ints: [0..7]=cnt, [16..24]=offs, [32..39]=fill

    int* cnt  = ctrl;
    int* offs = ctrl + 16;
    int* fill = ctrl + 32;

    hipMemsetAsync(ctrl, 0, 256, stream);
    hipMemsetAsync(d_out, 0, (size_t)out_size * sizeof(float), stream);

    k_gate<<<NTOK / 4, 256, 0, stream>>>(x, gw, xb, cnt, topi, topg);
    k_scan<<<1, 64, 0, stream>>>(cnt, offs, out + (size_t)NTOK * DDIM);
    k_scatter<<<(NTOK * TOPK) / 256, 256, 0, stream>>>(topi, topg, offs, fill, tok, gate);
    k_conv<<<2048, 256, 0, stream>>>((const float4*)w1, (const float4*)w2,
                                     (ushort4*)w1b, (ushort4*)w2b);
    // y = rt*8 + e, rt covers worst-case n_e=4096 (16 tiles of 256); actives lead.
    // FFN1: K=1024 -> 16 tiles, no split.  FFN2: K=2048 -> 32 tiles, split-K=2 (z) x 16.
    k_ffn8<DDIM, 16, true ><<<dim3(HDIM / 256, 128, 1), 512, 0, stream>>>(
        xb, w1b, b1, offs, tok, gate, hb, out);
    k_ffn8<HDIM, 16, false><<<dim3(DDIM / 256, 128, 2), 512, 0, stream>>>(
        hb, w2b, b2, offs, tok, gate, hb, out);
}

// Round 6
// 505.841 us; speedup vs baseline: 1.0692x; 1.0692x over previous
//
#include <hip/hip_runtime.h>
#include <stdint.h>

#define NTOK 4096   // B*S = 2*2048
#define DDIM 1024
#define HDIM 2048
#define NEXP 8
#define TOPK 2
#define NSLOT (NTOK * TOPK)   // 8192

typedef short bf16x8 __attribute__((ext_vector_type(8)));
typedef float f32x4 __attribute__((ext_vector_type(4)));

__device__ __forceinline__ unsigned short f2bf(float f) {
    union { float f; unsigned int u; } v; v.f = f;
    unsigned int r = v.u + 0x7fffu + ((v.u >> 16) & 1u);
    return (unsigned short)(r >> 16);
}

__device__ __forceinline__ void gload16(const void* g, void* l) {
    __builtin_amdgcn_global_load_lds(
        (const __attribute__((address_space(1))) unsigned int*)g,
        (__attribute__((address_space(3))) unsigned int*)l, 16, 0, 0);
}

// ---------------- gating: logits, top-2, gates, counts; also x -> bf16 ----------------
__global__ __launch_bounds__(256) void k_gate(
    const float* __restrict__ x, const float* __restrict__ gw,
    unsigned short* __restrict__ xb, int* __restrict__ cnt,
    int* __restrict__ topi, float* __restrict__ topg)
{
    int w = threadIdx.x >> 6, ln = threadIdx.x & 63;
    int n = blockIdx.x * 4 + w;
    const float* xr = x + (size_t)n * DDIM;
    float p[NEXP];
#pragma unroll
    for (int e = 0; e < NEXP; e++) p[e] = 0.f;
#pragma unroll
    for (int j = 0; j < DDIM / 64; j++) {
        int idx = ln + 64 * j;
        float xv = xr[idx];
        xb[(size_t)n * DDIM + idx] = f2bf(xv);
#pragma unroll
        for (int e = 0; e < NEXP; e++) p[e] += xv * gw[e * DDIM + idx];
    }
#pragma unroll
    for (int off = 32; off >= 1; off >>= 1) {
#pragma unroll
        for (int e = 0; e < NEXP; e++) p[e] += __shfl_xor(p[e], off, 64);
    }
    if (ln == 0) {
        int i0 = 0; float v0 = p[0];
#pragma unroll
        for (int e = 1; e < NEXP; e++) if (p[e] > v0) { v0 = p[e]; i0 = e; }
        int i1 = -1; float v1 = -3.0e38f;
#pragma unroll
        for (int e = 0; e < NEXP; e++) if (e != i0 && p[e] > v1) { v1 = p[e]; i1 = e; }
        float g0 = 1.f / (1.f + __expf(v1 - v0));  // softmax of [v0,v1], v0 >= v1
        float g1 = 1.f - g0;
        atomicAdd(&cnt[i0], 1); atomicAdd(&cnt[i1], 1);
        topi[n * 2] = i0; topi[n * 2 + 1] = i1;
        topg[n * 2] = g0; topg[n * 2 + 1] = g1;
    }
}

// ---------------- prefix-sum over expert counts + aux loss ----------------
__global__ void k_scan(const int* __restrict__ cnt, int* __restrict__ offs,
                       float* __restrict__ auxout)
{
    if (threadIdx.x == 0) {
        int o = 0; float aux = 0.f;
#pragma unroll
        for (int e = 0; e < NEXP; e++) {
            offs[e] = o; o += cnt[e];
            float l = (float)cnt[e] / (float)(NTOK * TOPK);
            aux += l * l;
        }
        offs[NEXP] = o;
        auxout[0] = 0.01f * (float)NEXP * aux;
    }
}

// -------- scatter token ids into expert buckets; record slot of each (n,k) --------
__global__ __launch_bounds__(256) void k_scatter(
    const int* __restrict__ topi,
    const int* __restrict__ offs, int* __restrict__ fill,
    int* __restrict__ tok, int* __restrict__ slotmap)
{
    int g = blockIdx.x * 256 + threadIdx.x;
    if (g >= NSLOT) return;
    int e = topi[g];
    int pos = atomicAdd(&fill[e], 1);
    int slot = offs[e] + pos;
    tok[slot] = g >> 1;
    slotmap[g] = slot;
}

// ---------------- fp32 -> bf16 weight conversion ----------------
__global__ __launch_bounds__(256) void k_conv(
    const float4* __restrict__ w1, const float4* __restrict__ w2,
    ushort4* __restrict__ w1b, ushort4* __restrict__ w2b)
{
    const int t1 = NEXP * HDIM * DDIM / 4;   // 4,194,304 vec4
    int stride = gridDim.x * blockDim.x;
    for (int i = blockIdx.x * 256 + threadIdx.x; i < 2 * t1; i += stride) {
        float4 v = (i < t1) ? w1[i] : w2[i - t1];
        ushort4 o;
        o.x = f2bf(v.x); o.y = f2bf(v.y); o.z = f2bf(v.z); o.w = f2bf(v.w);
        if (i < t1) w1b[i] = o; else w2b[i - t1] = o;
    }
}

// ------- combine: out[n] = sum_k g_k * (yp0[s_k] + yp1[s_k] + b2[e_k]) -------
__global__ __launch_bounds__(256) void k_comb(
    const float* __restrict__ yp0, const float* __restrict__ yp1,
    const int* __restrict__ topi, const float* __restrict__ topg,
    const int* __restrict__ slotmap, const float* __restrict__ b2,
    float* __restrict__ out)
{
    int n = blockIdx.x;
    int d4 = threadIdx.x;                       // float4 index, 256*4 = 1024 = DDIM
    int e0 = topi[n * 2], e1 = topi[n * 2 + 1];
    float g0 = topg[n * 2], g1 = topg[n * 2 + 1];
    size_t s0 = slotmap[n * 2], s1 = slotmap[n * 2 + 1];
    float4 a0 = ((const float4*)(yp0 + s0 * DDIM))[d4];
    float4 a1 = ((const float4*)(yp1 + s0 * DDIM))[d4];
    float4 c0 = ((const float4*)(yp0 + s1 * DDIM))[d4];
    float4 c1 = ((const float4*)(yp1 + s1 * DDIM))[d4];
    float4 bb0 = ((const float4*)(b2 + (size_t)e0 * DDIM))[d4];
    float4 bb1 = ((const float4*)(b2 + (size_t)e1 * DDIM))[d4];
    float4 r;
    r.x = g0 * (a0.x + a1.x + bb0.x) + g1 * (c0.x + c1.x + bb1.x);
    r.y = g0 * (a0.y + a1.y + bb0.y) + g1 * (c0.y + c1.y + bb1.y);
    r.z = g0 * (a0.z + a1.z + bb0.z) + g1 * (c0.z + c1.z + bb1.z);
    r.w = g0 * (a0.w + a1.w + bb0.w) + g1 * (c0.w + c1.w + bb1.w);
    ((float4*)(out + (size_t)n * DDIM))[d4] = r;
}

// =====================================================================================
// m201-geometry 8-phase FFN GEMM: BM=BN=256, BK=64, 512 thr = 8 waves (2M x 4N),
// wave-tile 128x64 = 8x4 frags of mfma_f32_16x16x32_bf16, 16-MFMA phase clusters.
// LDS: per buffer A 2 halves x 16KB + B 2 halves x 16KB = 64KB; x2 dbuf = 128KB.
// Swizzle: 16B chunk ^= (ldsrow & 7), applied on global SOURCE (LDS dest stays linear
// for global_load_lds) and on the ds_read chunk index.
// Stage rotation (2 gload_lds per slot):
//   P0:A1(b1,t+1) P1:A0(b0,t+2) P2:B0(b0,t+2) P3:B1(b0,t+2)+vmcnt(6) P4:A1(b0,t+2)
//   P5:A0(b1,t+3) P6:B0(b1,t+3) P7:B1(b1,t+3)+vmcnt(6). Last iter: vmcnt(0) at P3.
// FFN1 epilogue: silu+bias -> hbuf (bf16). FFN2 epilogue: plain fp32 stores of the
// split-K partial into yp0/yp1 (NO atomics, NO bias/gate -- k_comb applies those).
// =====================================================================================

#define VMCNT(n) asm volatile("s_waitcnt vmcnt(" #n ")" ::: "memory")
#define SBAR do { __builtin_amdgcn_sched_barrier(0); __builtin_amdgcn_s_barrier(); } while(0)
#define PRIO1 __builtin_amdgcn_s_setprio(1)
#define PRIO0 __builtin_amdgcn_s_setprio(0)

#define ST_A(b,h,tt) do { \
    gload16(aSrc[h][0] + (size_t)(tt)*64, smem + (b)*65536 + (h)*16384 +        w*1024); \
    gload16(aSrc[h][1] + (size_t)(tt)*64, smem + (b)*65536 + (h)*16384 + 8192 + w*1024); } while(0)
#define ST_B(b,h,tt) do { \
    gload16(bSrc[h][0] + (size_t)(tt)*64, smem + (b)*65536 + 32768 + (h)*16384 +        w*1024); \
    gload16(bSrc[h][1] + (size_t)(tt)*64, smem + (b)*65536 + 32768 + (h)*16384 + 8192 + w*1024); } while(0)

#define LDA(DST,b,mh) do { _Pragma("unroll") for (int mi=0;mi<4;mi++) { _Pragma("unroll") for (int ks=0;ks<2;ks++) { \
    DST[mi][ks] = *(const bf16x8*)(smem + (b)*65536 + (mh)*16384 + (wm*64 + mi*16 + ln15)*128 + colx[ks]); }} } while(0)
#define LDB(b,nh) do { _Pragma("unroll") for (int ni=0;ni<2;ni++) { _Pragma("unroll") for (int ks=0;ks<2;ks++) { \
    bb[ni][ks] = *(const bf16x8*)(smem + (b)*65536 + 32768 + (nh)*16384 + (wn*32 + ni*16 + ln15)*128 + colx[ks]); }} } while(0)
#define QUAD16(mh,nh,ASET) do { _Pragma("unroll") for (int mi=0;mi<4;mi++) { _Pragma("unroll") for (int ni=0;ni<2;ni++) { _Pragma("unroll") for (int ks=0;ks<2;ks++) { \
    acc[(mh)*4+mi][(nh)*2+ni] = __builtin_amdgcn_mfma_f32_16x16x32_bf16(ASET[mi][ks], bb[ni][ks], acc[(mh)*4+mi][(nh)*2+ni], 0,0,0); }}} } while(0)

#define ITER(LAST, t) do { \
  LDA(aA,0,0); LDB(0,0); ST_A(1,1,(t)+1); \
  SBAR; PRIO1; QUAD16(0,0,aA); PRIO0; SBAR; \
  LDA(aB,0,1); if(!(LAST)) ST_A(0,0,(t)+2); \
  SBAR; PRIO1; QUAD16(1,0,aB); PRIO0; SBAR; \
  LDB(0,1); if(!(LAST)) ST_B(0,0,(t)+2); \
  SBAR; PRIO1; QUAD16(1,1,aB); PRIO0; SBAR; \
  if(!(LAST)) ST_B(0,1,(t)+2); \
  SBAR; PRIO1; QUAD16(0,1,aA); PRIO0; \
  if(LAST) { VMCNT(0); } else { VMCNT(6); } SBAR; \
  LDA(aA,1,0); LDB(1,0); if(!(LAST)) ST_A(0,1,(t)+2); \
  SBAR; PRIO1; QUAD16(0,0,aA); PRIO0; SBAR; \
  LDA(aB,1,1); if(!(LAST)) ST_A(1,0,(t)+3); \
  SBAR; PRIO1; QUAD16(1,0,aB); PRIO0; SBAR; \
  LDB(1,1); if(!(LAST)) ST_B(1,0,(t)+3); \
  SBAR; PRIO1; QUAD16(1,1,aB); PRIO0; SBAR; \
  if(!(LAST)) ST_B(1,1,(t)+3); \
  SBAR; PRIO1; QUAD16(0,1,aA); PRIO0; \
  if(!(LAST)) { VMCNT(6); } SBAR; \
} while(0)

// KTOT = full K (row pitch); TBLK = K-tiles per block (split-K via blockIdx.z)
template<int KTOT, int TBLK, bool IS_FFN1>
__global__ __launch_bounds__(512, 2) void k_ffn8(
    const unsigned short* __restrict__ Abase,
    const unsigned short* __restrict__ Wb,
    const float* __restrict__ bias,
    const int* __restrict__ offs,
    const int* __restrict__ tok,
    unsigned short* __restrict__ hbuf,
    float* __restrict__ yp0,
    float* __restrict__ yp1)
{
    constexpr int NCOLS = IS_FFN1 ? HDIM : DDIM;

    int e = blockIdx.y & 7, rt = blockIdx.y >> 3;
    int soff = offs[e];
    int n_e = offs[e + 1] - soff;
    int row0 = rt * 256;
    if (row0 >= n_e) return;               // block-uniform exit, before any barrier
    int ncol0 = blockIdx.x * 256;
    int koff = blockIdx.z * (TBLK * 64);

    __shared__ __align__(16) char smem[131072];

    int tid = threadIdx.x;
    int w = tid >> 6, ln = tid & 63;
    int wm = w >> 2, wn = w & 3;
    int ln15 = ln & 15, g4 = ln >> 4;
    int colx[2];
#pragma unroll
    for (int ks = 0; ks < 2; ks++) colx[ks] = ((ks * 4 + g4) ^ (ln15 & 7)) * 16;

    // ---- per-lane stage source pointers (swizzle pre-applied on global address) ----
    const unsigned short* aSrc[2][2];
#pragma unroll
    for (int h = 0; h < 2; h++)
#pragma unroll
        for (int i = 0; i < 2; i++) {
            int rho = i * 64 + (tid >> 3);
            int trow = (rho >> 6) * 128 + h * 64 + (rho & 63);
            int csrc = (tid & 7) ^ (rho & 7);
            int r = row0 + trow; if (r > n_e - 1) r = n_e - 1;
            size_t grow = IS_FFN1 ? (size_t)tok[soff + r] : (size_t)(soff + r);
            aSrc[h][i] = Abase + grow * KTOT + koff + csrc * 8;
        }
    const unsigned short* Wexp = Wb + (size_t)e * NCOLS * KTOT;
    const unsigned short* bSrc[2][2];
#pragma unroll
    for (int h = 0; h < 2; h++)
#pragma unroll
        for (int i = 0; i < 2; i++) {
            int rho = i * 64 + (tid >> 3);
            int tcol = (rho >> 5) * 64 + h * 32 + (rho & 31);
            int csrc = (tid & 7) ^ (rho & 7);
            bSrc[h][i] = Wexp + (size_t)(ncol0 + tcol) * KTOT + koff + csrc * 8;
        }

    f32x4 acc[8][4];
#pragma unroll
    for (int m = 0; m < 8; m++)
#pragma unroll
        for (int n = 0; n < 4; n++) acc[m][n] = (f32x4)0.f;

    bf16x8 aA[4][2], aB[4][2], bb[2][2];

    // ---- prologue: tile0 fully, tile1 minus A1 = 14 loads; 6 stay in flight ----
    ST_A(0, 0, 0);
    ST_B(0, 0, 0);
    ST_A(0, 1, 0);
    ST_B(0, 1, 0);
    ST_A(1, 0, 1);
    ST_B(1, 0, 1);
    ST_B(1, 1, 1);
    VMCNT(6);
    SBAR;

    for (int t = 0; t + 2 < TBLK; t += 2) ITER(false, t);
    ITER(true, TBLK - 2);

    // ---- epilogue: C frag layout col=ln15 (n-side), row=g4*4+q (m-side) ----
    if (IS_FFN1) {
        float bv[4];
#pragma unroll
        for (int nj = 0; nj < 4; nj++)
            bv[nj] = bias[e * NCOLS + ncol0 + wn * 64 + nj * 16 + ln15];
#pragma unroll
        for (int mi = 0; mi < 8; mi++) {
#pragma unroll
            for (int q = 0; q < 4; q++) {
                int r = row0 + wm * 128 + mi * 16 + g4 * 4 + q;
                if (r < n_e) {
#pragma unroll
                    for (int nj = 0; nj < 4; nj++) {
                        int col = ncol0 + wn * 64 + nj * 16 + ln15;
                        float v = acc[mi][nj][q] + bv[nj];
                        float s = v / (1.f + __expf(-v));   // silu
                        hbuf[(size_t)(soff + r) * HDIM + col] = f2bf(s);
                    }
                }
            }
        }
    } else {
        float* ydst = (blockIdx.z == 0) ? yp0 : yp1;
#pragma unroll
        for (int mi = 0; mi < 8; mi++) {
#pragma unroll
            for (int q = 0; q < 4; q++) {
                int r = row0 + wm * 128 + mi * 16 + g4 * 4 + q;
                if (r < n_e) {
                    size_t row = (size_t)(soff + r) * DDIM;
#pragma unroll
                    for (int nj = 0; nj < 4; nj++) {
                        int col = ncol0 + wn * 64 + nj * 16 + ln15;
                        ydst[row + col] = acc[mi][nj][q];   // plain coalesced store
                    }
                }
            }
        }
    }
}

extern "C" void kernel_launch(void* const* d_in, const int* in_sizes, int n_in,
                              void* d_out, int out_size, void* d_ws, size_t ws_size,
                              hipStream_t stream)
{
    const float* x  = (const float*)d_in[0];
    const float* gw = (const float*)d_in[1];
    const float* w1 = (const float*)d_in[2];
    const float* b1 = (const float*)d_in[3];
    const float* w2 = (const float*)d_in[4];
    const float* b2 = (const float*)d_in[5];
    float* out = (float*)d_out;

    char* ws = (char*)d_ws;
    size_t off = 0;
    auto alloc = [&](size_t bytes) {
        char* p = ws + off; off += (bytes + 255) & ~(size_t)255; return p;
    };
    unsigned short* xb  = (unsigned short*)alloc((size_t)NTOK * DDIM * 2);        // 8.4 MB
    unsigned short* w1b = (unsigned short*)alloc((size_t)NEXP * HDIM * DDIM * 2); // 33.5 MB
    unsigned short* w2b = (unsigned short*)alloc((size_t)NEXP * DDIM * HDIM * 2); // 33.5 MB
    unsigned short* hb  = (unsigned short*)alloc((size_t)NSLOT * HDIM * 2);       // 33.5 MB
    float* yp1 = (float*)alloc((size_t)NSLOT * DDIM * 4);                         // 33.5 MB
    int*   tok  = (int*)alloc(NSLOT * 4);
    int*   slotmap = (int*)alloc(NSLOT * 4);
    int*   topi = (int*)alloc(NSLOT * 4);
    float* topg = (float*)alloc(NSLOT * 4);
    int*   ctrl = (int*)alloc(256);   // ints: [0..7]=cnt, [16..24]=offs, [32..39]=fill
    // yp0 ALIASES xb+w1b (both dead once FFN1 completes; rewritten next call)
    float* yp0 = (float*)ws;                                                      // 33.5 MB

    int* cnt  = ctrl;
    int* offs = ctrl + 16;
    int* fill = ctrl + 32;

    hipMemsetAsync(ctrl, 0, 256, stream);

    k_gate<<<NTOK / 4, 256, 0, stream>>>(x, gw, xb, cnt, topi, topg);
    k_scan<<<1, 64, 0, stream>>>(cnt, offs, out + (size_t)NTOK * DDIM);
    k_scatter<<<NSLOT / 256, 256, 0, stream>>>(topi, offs, fill, tok, slotmap);
    k_conv<<<2048, 256, 0, stream>>>((const float4*)w1, (const float4*)w2,
                                     (ushort4*)w1b, (ushort4*)w2b);
    // y = rt*8 + e, rt covers worst-case n_e=4096 (16 tiles of 256); actives lead.
    // FFN1: K=1024 -> 16 tiles.  FFN2: K=2048 -> 32 tiles, split-K=2 (z) x 16.
    k_ffn8<DDIM, 16, true ><<<dim3(HDIM / 256, 128, 1), 512, 0, stream>>>(
        xb, w1b, b1, offs, tok, hb, yp0, yp1);
    k_ffn8<HDIM, 16, false><<<dim3(DDIM / 256, 128, 2), 512, 0, stream>>>(
        hb, w2b, b2, offs, tok, hb, yp0, yp1);
    k_comb<<<NTOK, 256, 0, stream>>>(yp0, yp1, topi, topg, slotmap, b2, out);
}

// Round 7
// 386.477 us; speedup vs baseline: 1.3994x; 1.3089x over previous
//
#include <hip/hip_runtime.h>
#include <stdint.h>

#define NTOK 4096   // B*S = 2*2048
#define DDIM 1024
#define HDIM 2048
#define NEXP 8
#define TOPK 2
#define NSLOT (NTOK * TOPK)   // 8192

typedef short bf16x8 __attribute__((ext_vector_type(8)));
typedef float f32x4 __attribute__((ext_vector_type(4)));

__device__ __forceinline__ unsigned short f2bf(float f) {
    union { float f; unsigned int u; } v; v.f = f;
    unsigned int r = v.u + 0x7fffu + ((v.u >> 16) & 1u);
    return (unsigned short)(r >> 16);
}

__device__ __forceinline__ void gload16(const void* g, void* l) {
    __builtin_amdgcn_global_load_lds(
        (const __attribute__((address_space(1))) unsigned int*)g,
        (__attribute__((address_space(3))) unsigned int*)l, 16, 0, 0);
}

// ------- gating: logits, top-2, gates; x -> bf16.  NO ATOMICS (was 103us from
// 8192 same-line atomicAdds; counts now derived in k_route). float4 vectorized. -------
__global__ __launch_bounds__(256) void k_gate(
    const float* __restrict__ x, const float* __restrict__ gw,
    unsigned short* __restrict__ xb,
    int* __restrict__ topi, float* __restrict__ topg)
{
    int w = threadIdx.x >> 6, ln = threadIdx.x & 63;
    int n = blockIdx.x * 4 + w;
    const float4* xr4 = (const float4*)(x + (size_t)n * DDIM);
    const float4* gw4 = (const float4*)gw;
    ushort4* xb4 = (ushort4*)(xb + (size_t)n * DDIM);
    float p[NEXP];
#pragma unroll
    for (int e = 0; e < NEXP; e++) p[e] = 0.f;
#pragma unroll
    for (int j = 0; j < DDIM / 256; j++) {          // 4 iters: 4 floats/lane each
        int idx = ln + 64 * j;
        float4 v = xr4[idx];
        ushort4 o;
        o.x = f2bf(v.x); o.y = f2bf(v.y); o.z = f2bf(v.z); o.w = f2bf(v.w);
        xb4[idx] = o;
#pragma unroll
        for (int e = 0; e < NEXP; e++) {
            float4 g4 = gw4[e * (DDIM / 4) + idx];
            p[e] += v.x * g4.x + v.y * g4.y + v.z * g4.z + v.w * g4.w;
        }
    }
#pragma unroll
    for (int off = 32; off >= 1; off >>= 1) {
#pragma unroll
        for (int e = 0; e < NEXP; e++) p[e] += __shfl_xor(p[e], off, 64);
    }
    if (ln == 0) {
        int i0 = 0; float v0 = p[0];
#pragma unroll
        for (int e = 1; e < NEXP; e++) if (p[e] > v0) { v0 = p[e]; i0 = e; }
        int i1 = -1; float v1 = -3.0e38f;
#pragma unroll
        for (int e = 0; e < NEXP; e++) if (e != i0 && p[e] > v1) { v1 = p[e]; i1 = e; }
        float g0 = 1.f / (1.f + __expf(v1 - v0));  // softmax of [v0,v1], v0 >= v1
        float g1 = 1.f - g0;
        topi[n * 2] = i0; topi[n * 2 + 1] = i1;
        topg[n * 2] = g0; topg[n * 2 + 1] = g1;
    }
}

// ------- routing: counts, offsets, stable slot assignment, aux loss.
// Single block, 1024 threads, zero global atomics. Thread t owns items 8t..8t+7.
// Counts packed 2 experts/u32 (16-bit fields); shfl_up inclusive scan per wave;
// serial cross-wave scan by thread 0 (16 entries). Slot order = stable by g. -------
__global__ __launch_bounds__(1024) void k_route(
    const int* __restrict__ topi,
    int* __restrict__ offs_g,
    int* __restrict__ tok, int* __restrict__ slotmap,
    float* __restrict__ auxout)
{
    __shared__ unsigned int wtot[16][4];
    __shared__ unsigned int wbase[16][4];
    __shared__ int offs_l[9];
    int tid = threadIdx.x;
    int ln = tid & 63, wv = tid >> 6;

    const int4* tp = (const int4*)topi + tid * 2;
    int4 a = tp[0], b = tp[1];
    int e_[8] = { a.x, a.y, a.z, a.w, b.x, b.y, b.z, b.w };

    unsigned int P[4] = {0, 0, 0, 0};
#pragma unroll
    for (int k = 0; k < 8; k++) {
#pragma unroll
        for (int e = 0; e < 8; e++)
            if (e_[k] == e) P[e >> 1] += (e & 1) ? 0x10000u : 1u;
    }
    unsigned int S0 = P[0], S1 = P[1], S2 = P[2], S3 = P[3];
#pragma unroll
    for (int d = 1; d < 64; d <<= 1) {
        unsigned int t0 = __shfl_up(S0, d, 64), t1 = __shfl_up(S1, d, 64);
        unsigned int t2 = __shfl_up(S2, d, 64), t3 = __shfl_up(S3, d, 64);
        if (ln >= d) { S0 += t0; S1 += t1; S2 += t2; S3 += t3; }
    }
    if (ln == 63) { wtot[wv][0] = S0; wtot[wv][1] = S1; wtot[wv][2] = S2; wtot[wv][3] = S3; }
    __syncthreads();
    if (tid == 0) {
        unsigned int run[4] = {0, 0, 0, 0};
        for (int w2 = 0; w2 < 16; w2++) {
#pragma unroll
            for (int j = 0; j < 4; j++) {
                unsigned int t = wtot[w2][j]; wbase[w2][j] = run[j]; run[j] += t;
            }
        }
        int o = 0; float aux = 0.f;
#pragma unroll
        for (int e = 0; e < 8; e++) {
            int c = (run[e >> 1] >> ((e & 1) * 16)) & 0xFFFF;
            offs_l[e] = o; offs_g[e] = o; o += c;
            float l = (float)c / (float)NSLOT;
            aux += l * l;
        }
        offs_l[8] = o; offs_g[8] = o;
        auxout[0] = 0.01f * (float)NEXP * aux;
    }
    __syncthreads();
    unsigned int EX[4];
    EX[0] = S0 - P[0] + wbase[wv][0]; EX[1] = S1 - P[1] + wbase[wv][1];
    EX[2] = S2 - P[2] + wbase[wv][2]; EX[3] = S3 - P[3] + wbase[wv][3];
#pragma unroll
    for (int k = 0; k < 8; k++) {
        int e = e_[k];
        int r = 0;
#pragma unroll
        for (int k2 = 0; k2 < 8; k2++)
            if (k2 < k && e_[k2] == e) r++;
        int base = 0;
#pragma unroll
        for (int ee = 0; ee < 8; ee++)
            if (e == ee) base = (int)((EX[ee >> 1] >> ((ee & 1) * 16)) & 0xFFFF);
        int g = tid * 8 + k;
        int slot = offs_l[e] + base + r;
        tok[slot] = g >> 1;
        slotmap[g] = slot;
    }
}

// ---------------- fp32 -> bf16 weight conversion ----------------
__global__ __launch_bounds__(256) void k_conv(
    const float4* __restrict__ w1, const float4* __restrict__ w2,
    ushort4* __restrict__ w1b, ushort4* __restrict__ w2b)
{
    const int t1 = NEXP * HDIM * DDIM / 4;   // 4,194,304 vec4
    int stride = gridDim.x * blockDim.x;
    for (int i = blockIdx.x * 256 + threadIdx.x; i < 2 * t1; i += stride) {
        float4 v = (i < t1) ? w1[i] : w2[i - t1];
        ushort4 o;
        o.x = f2bf(v.x); o.y = f2bf(v.y); o.z = f2bf(v.z); o.w = f2bf(v.w);
        if (i < t1) w1b[i] = o; else w2b[i - t1] = o;
    }
}

// ------- combine: out[n] = sum_k g_k * (yp0[s_k] + yp1[s_k] + b2[e_k]) -------
__global__ __launch_bounds__(256) void k_comb(
    const float* __restrict__ yp0, const float* __restrict__ yp1,
    const int* __restrict__ topi, const float* __restrict__ topg,
    const int* __restrict__ slotmap, const float* __restrict__ b2,
    float* __restrict__ out)
{
    int n = blockIdx.x;
    int d4 = threadIdx.x;                       // float4 index, 256*4 = 1024 = DDIM
    int e0 = topi[n * 2], e1 = topi[n * 2 + 1];
    float g0 = topg[n * 2], g1 = topg[n * 2 + 1];
    size_t s0 = slotmap[n * 2], s1 = slotmap[n * 2 + 1];
    float4 a0 = ((const float4*)(yp0 + s0 * DDIM))[d4];
    float4 a1 = ((const float4*)(yp1 + s0 * DDIM))[d4];
    float4 c0 = ((const float4*)(yp0 + s1 * DDIM))[d4];
    float4 c1 = ((const float4*)(yp1 + s1 * DDIM))[d4];
    float4 bb0 = ((const float4*)(b2 + (size_t)e0 * DDIM))[d4];
    float4 bb1 = ((const float4*)(b2 + (size_t)e1 * DDIM))[d4];
    float4 r;
    r.x = g0 * (a0.x + a1.x + bb0.x) + g1 * (c0.x + c1.x + bb1.x);
    r.y = g0 * (a0.y + a1.y + bb0.y) + g1 * (c0.y + c1.y + bb1.y);
    r.z = g0 * (a0.z + a1.z + bb0.z) + g1 * (c0.z + c1.z + bb1.z);
    r.w = g0 * (a0.w + a1.w + bb0.w) + g1 * (c0.w + c1.w + bb1.w);
    ((float4*)(out + (size_t)n * DDIM))[d4] = r;
}

// =====================================================================================
// m201-geometry 8-phase FFN GEMM: BM=BN=256, BK=64, 512 thr = 8 waves (2M x 4N),
// wave-tile 128x64 = 8x4 frags of mfma_f32_16x16x32_bf16, 16-MFMA phase clusters.
// LDS: per buffer A 2 halves x 16KB + B 2 halves x 16KB = 64KB; x2 dbuf = 128KB.
// Swizzle: 16B chunk ^= (ldsrow & 7), applied on global SOURCE (LDS dest stays linear
// for global_load_lds) and on the ds_read chunk index.
// Stage rotation (2 gload_lds per slot):
//   P0:A1(b1,t+1) P1:A0(b0,t+2) P2:B0(b0,t+2) P3:B1(b0,t+2)+vmcnt(6) P4:A1(b0,t+2)
//   P5:A0(b1,t+3) P6:B0(b1,t+3) P7:B1(b1,t+3)+vmcnt(6). Last iter: vmcnt(0) at P3.
// FFN1 epilogue: silu+bias -> hbuf (bf16). FFN2 epilogue: plain fp32 stores of the
// split-K partial into yp0/yp1 (NO atomics, NO bias/gate -- k_comb applies those).
// =====================================================================================

#define VMCNT(n) asm volatile("s_waitcnt vmcnt(" #n ")" ::: "memory")
#define SBAR do { __builtin_amdgcn_sched_barrier(0); __builtin_amdgcn_s_barrier(); } while(0)
#define PRIO1 __builtin_amdgcn_s_setprio(1)
#define PRIO0 __builtin_amdgcn_s_setprio(0)

#define ST_A(b,h,tt) do { \
    gload16(aSrc[h][0] + (size_t)(tt)*64, smem + (b)*65536 + (h)*16384 +        w*1024); \
    gload16(aSrc[h][1] + (size_t)(tt)*64, smem + (b)*65536 + (h)*16384 + 8192 + w*1024); } while(0)
#define ST_B(b,h,tt) do { \
    gload16(bSrc[h][0] + (size_t)(tt)*64, smem + (b)*65536 + 32768 + (h)*16384 +        w*1024); \
    gload16(bSrc[h][1] + (size_t)(tt)*64, smem + (b)*65536 + 32768 + (h)*16384 + 8192 + w*1024); } while(0)

#define LDA(DST,b,mh) do { _Pragma("unroll") for (int mi=0;mi<4;mi++) { _Pragma("unroll") for (int ks=0;ks<2;ks++) { \
    DST[mi][ks] = *(const bf16x8*)(smem + (b)*65536 + (mh)*16384 + (wm*64 + mi*16 + ln15)*128 + colx[ks]); }} } while(0)
#define LDB(b,nh) do { _Pragma("unroll") for (int ni=0;ni<2;ni++) { _Pragma("unroll") for (int ks=0;ks<2;ks++) { \
    bb[ni][ks] = *(const bf16x8*)(smem + (b)*65536 + 32768 + (nh)*16384 + (wn*32 + ni*16 + ln15)*128 + colx[ks]); }} } while(0)
#define QUAD16(mh,nh,ASET) do { _Pragma("unroll") for (int mi=0;mi<4;mi++) { _Pragma("unroll") for (int ni=0;ni<2;ni++) { _Pragma("unroll") for (int ks=0;ks<2;ks++) { \
    acc[(mh)*4+mi][(nh)*2+ni] = __builtin_amdgcn_mfma_f32_16x16x32_bf16(ASET[mi][ks], bb[ni][ks], acc[(mh)*4+mi][(nh)*2+ni], 0,0,0); }}} } while(0)

#define ITER(LAST, t) do { \
  LDA(aA,0,0); LDB(0,0); ST_A(1,1,(t)+1); \
  SBAR; PRIO1; QUAD16(0,0,aA); PRIO0; SBAR; \
  LDA(aB,0,1); if(!(LAST)) ST_A(0,0,(t)+2); \
  SBAR; PRIO1; QUAD16(1,0,aB); PRIO0; SBAR; \
  LDB(0,1); if(!(LAST)) ST_B(0,0,(t)+2); \
  SBAR; PRIO1; QUAD16(1,1,aB); PRIO0; SBAR; \
  if(!(LAST)) ST_B(0,1,(t)+2); \
  SBAR; PRIO1; QUAD16(0,1,aA); PRIO0; \
  if(LAST) { VMCNT(0); } else { VMCNT(6); } SBAR; \
  LDA(aA,1,0); LDB(1,0); if(!(LAST)) ST_A(0,1,(t)+2); \
  SBAR; PRIO1; QUAD16(0,0,aA); PRIO0; SBAR; \
  LDA(aB,1,1); if(!(LAST)) ST_A(1,0,(t)+3); \
  SBAR; PRIO1; QUAD16(1,0,aB); PRIO0; SBAR; \
  LDB(1,1); if(!(LAST)) ST_B(1,0,(t)+3); \
  SBAR; PRIO1; QUAD16(1,1,aB); PRIO0; SBAR; \
  if(!(LAST)) ST_B(1,1,(t)+3); \
  SBAR; PRIO1; QUAD16(0,1,aA); PRIO0; \
  if(!(LAST)) { VMCNT(6); } SBAR; \
} while(0)

// KTOT = full K (row pitch); TBLK = K-tiles per block (split-K via blockIdx.z)
template<int KTOT, int TBLK, bool IS_FFN1>
__global__ __launch_bounds__(512, 2) void k_ffn8(
    const unsigned short* __restrict__ Abase,
    const unsigned short* __restrict__ Wb,
    const float* __restrict__ bias,
    const int* __restrict__ offs,
    const int* __restrict__ tok,
    unsigned short* __restrict__ hbuf,
    float* __restrict__ yp0,
    float* __restrict__ yp1)
{
    constexpr int NCOLS = IS_FFN1 ? HDIM : DDIM;

    int e = blockIdx.y & 7, rt = blockIdx.y >> 3;
    int soff = offs[e];
    int n_e = offs[e + 1] - soff;
    int row0 = rt * 256;
    if (row0 >= n_e) return;               // block-uniform exit, before any barrier
    int ncol0 = blockIdx.x * 256;
    int koff = blockIdx.z * (TBLK * 64);

    __shared__ __align__(16) char smem[131072];

    int tid = threadIdx.x;
    int w = tid >> 6, ln = tid & 63;
    int wm = w >> 2, wn = w & 3;
    int ln15 = ln & 15, g4 = ln >> 4;
    int colx[2];
#pragma unroll
    for (int ks = 0; ks < 2; ks++) colx[ks] = ((ks * 4 + g4) ^ (ln15 & 7)) * 16;

    // ---- per-lane stage source pointers (swizzle pre-applied on global address) ----
    const unsigned short* aSrc[2][2];
#pragma unroll
    for (int h = 0; h < 2; h++)
#pragma unroll
        for (int i = 0; i < 2; i++) {
            int rho = i * 64 + (tid >> 3);
            int trow = (rho >> 6) * 128 + h * 64 + (rho & 63);
            int csrc = (tid & 7) ^ (rho & 7);
            int r = row0 + trow; if (r > n_e - 1) r = n_e - 1;
            size_t grow = IS_FFN1 ? (size_t)tok[soff + r] : (size_t)(soff + r);
            aSrc[h][i] = Abase + grow * KTOT + koff + csrc * 8;
        }
    const unsigned short* Wexp = Wb + (size_t)e * NCOLS * KTOT;
    const unsigned short* bSrc[2][2];
#pragma unroll
    for (int h = 0; h < 2; h++)
#pragma unroll
        for (int i = 0; i < 2; i++) {
            int rho = i * 64 + (tid >> 3);
            int tcol = (rho >> 5) * 64 + h * 32 + (rho & 31);
            int csrc = (tid & 7) ^ (rho & 7);
            bSrc[h][i] = Wexp + (size_t)(ncol0 + tcol) * KTOT + koff + csrc * 8;
        }

    f32x4 acc[8][4];
#pragma unroll
    for (int m = 0; m < 8; m++)
#pragma unroll
        for (int n = 0; n < 4; n++) acc[m][n] = (f32x4)0.f;

    bf16x8 aA[4][2], aB[4][2], bb[2][2];

    // ---- prologue: tile0 fully, tile1 minus A1 = 14 loads; 6 stay in flight ----
    ST_A(0, 0, 0);
    ST_B(0, 0, 0);
    ST_A(0, 1, 0);
    ST_B(0, 1, 0);
    ST_A(1, 0, 1);
    ST_B(1, 0, 1);
    ST_B(1, 1, 1);
    VMCNT(6);
    SBAR;

    for (int t = 0; t + 2 < TBLK; t += 2) ITER(false, t);
    ITER(true, TBLK - 2);

    // ---- epilogue: C frag layout col=ln15 (n-side), row=g4*4+q (m-side) ----
    if (IS_FFN1) {
        float bv[4];
#pragma unroll
        for (int nj = 0; nj < 4; nj++)
            bv[nj] = bias[e * NCOLS + ncol0 + wn * 64 + nj * 16 + ln15];
#pragma unroll
        for (int mi = 0; mi < 8; mi++) {
#pragma unroll
            for (int q = 0; q < 4; q++) {
                int r = row0 + wm * 128 + mi * 16 + g4 * 4 + q;
                if (r < n_e) {
#pragma unroll
                    for (int nj = 0; nj < 4; nj++) {
                        int col = ncol0 + wn * 64 + nj * 16 + ln15;
                        float v = acc[mi][nj][q] + bv[nj];
                        float s = v / (1.f + __expf(-v));   // silu
                        hbuf[(size_t)(soff + r) * HDIM + col] = f2bf(s);
                    }
                }
            }
        }
    } else {
        float* ydst = (blockIdx.z == 0) ? yp0 : yp1;
#pragma unroll
        for (int mi = 0; mi < 8; mi++) {
#pragma unroll
            for (int q = 0; q < 4; q++) {
                int r = row0 + wm * 128 + mi * 16 + g4 * 4 + q;
                if (r < n_e) {
                    size_t row = (size_t)(soff + r) * DDIM;
#pragma unroll
                    for (int nj = 0; nj < 4; nj++) {
                        int col = ncol0 + wn * 64 + nj * 16 + ln15;
                        ydst[row + col] = acc[mi][nj][q];   // plain coalesced store
                    }
                }
            }
        }
    }
}

extern "C" void kernel_launch(void* const* d_in, const int* in_sizes, int n_in,
                              void* d_out, int out_size, void* d_ws, size_t ws_size,
                              hipStream_t stream)
{
    const float* x  = (const float*)d_in[0];
    const float* gw = (const float*)d_in[1];
    const float* w1 = (const float*)d_in[2];
    const float* b1 = (const float*)d_in[3];
    const float* w2 = (const float*)d_in[4];
    const float* b2 = (const float*)d_in[5];
    float* out = (float*)d_out;

    char* ws = (char*)d_ws;
    size_t off = 0;
    auto alloc = [&](size_t bytes) {
        char* p = ws + off; off += (bytes + 255) & ~(size_t)255; return p;
    };
    unsigned short* xb  = (unsigned short*)alloc((size_t)NTOK * DDIM * 2);        // 8.4 MB
    unsigned short* w1b = (unsigned short*)alloc((size_t)NEXP * HDIM * DDIM * 2); // 33.5 MB
    unsigned short* w2b = (unsigned short*)alloc((size_t)NEXP * DDIM * HDIM * 2); // 33.5 MB
    unsigned short* hb  = (unsigned short*)alloc((size_t)NSLOT * HDIM * 2);       // 33.5 MB
    float* yp1 = (float*)alloc((size_t)NSLOT * DDIM * 4);                         // 33.5 MB
    int*   tok  = (int*)alloc(NSLOT * 4);
    int*   slotmap = (int*)alloc(NSLOT * 4);
    int*   topi = (int*)alloc(NSLOT * 4);
    float* topg = (float*)alloc(NSLOT * 4);
    int*   ctrl = (int*)alloc(256);   // ints: [16..24]=offs
    // yp0 ALIASES xb+w1b (both dead once FFN1 completes; rewritten next call)
    float* yp0 = (float*)ws;                                                      // 33.5 MB

    int* offs = ctrl + 16;

    k_gate<<<NTOK / 4, 256, 0, stream>>>(x, gw, xb, topi, topg);
    k_route<<<1, 1024, 0, stream>>>(topi, offs, tok, slotmap,
                                    out + (size_t)NTOK * DDIM);
    k_conv<<<2048, 256, 0, stream>>>((const float4*)w1, (const float4*)w2,
                                     (ushort4*)w1b, (ushort4*)w2b);
    // y = rt*8 + e, rt covers worst-case n_e=4096 (16 tiles of 256); actives lead.
    // FFN1: K=1024 -> 16 tiles.  FFN2: K=2048 -> 32 tiles, split-K=2 (z) x 16.
    k_ffn8<DDIM, 16, true ><<<dim3(HDIM / 256, 128, 1), 512, 0, stream>>>(
        xb, w1b, b1, offs, tok, hb, yp0, yp1);
    k_ffn8<HDIM, 16, false><<<dim3(DDIM / 256, 128, 2), 512, 0, stream>>>(
        hb, w2b, b2, offs, tok, hb, yp0, yp1);
    k_comb<<<NTOK, 256, 0, stream>>>(yp0, yp1, topi, topg, slotmap, b2, out);
}